// Round 1
// baseline (194.490 us; speedup 1.0000x reference)
//
#include <hip/hip_runtime.h>
#include <stdint.h>

// ---------------------------------------------------------------------------
// Types
// ---------------------------------------------------------------------------
typedef __attribute__((ext_vector_type(8))) __bf16 bf16x8;
typedef __attribute__((ext_vector_type(8))) unsigned short u16x8;
typedef __attribute__((ext_vector_type(4))) unsigned short u16x4;
typedef __attribute__((ext_vector_type(4))) short s16x4;
typedef __attribute__((ext_vector_type(4))) float f32x4;

typedef unsigned int u32_as1 __attribute__((address_space(1)));
typedef unsigned int u32_as3 __attribute__((address_space(3)));

// fp32 -> bf16 round-to-nearest-even (inputs are finite normals; no NaN path)
__device__ __forceinline__ unsigned short f2bf(float f) {
  unsigned int u = __float_as_uint(f);
  u += 0x7fffu + ((u >> 16) & 1u);
  return (unsigned short)(u >> 16);
}

__device__ __forceinline__ bf16x8 ld_frag(const unsigned short* p) {
  return __builtin_bit_cast(bf16x8, *(const u16x8*)p);
}

// K=16 bf16 MFMA: A/B are 4 bf16 (as short4). C row=quad*4+r, col=lane&15;
// A[m=lane&15][k=quad*4+j]; B[k=quad*4+j][n=lane&15].
__device__ __forceinline__ f32x4 mfma16(s16x4 a, s16x4 b, f32x4 c) {
#if __has_builtin(__builtin_amdgcn_mfma_f32_16x16x16bf16_1k)
  return __builtin_amdgcn_mfma_f32_16x16x16bf16_1k(a, b, c, 0, 0, 0);
#elif __has_builtin(__builtin_amdgcn_mfma_f32_16x16x16_bf16_1k)
  return __builtin_amdgcn_mfma_f32_16x16x16_bf16_1k(a, b, c, 0, 0, 0);
#else
  asm volatile("v_mfma_f32_16x16x16_bf16 %0, %1, %2, %0"
               : "+v"(c) : "v"(a), "v"(b));
  return c;
#endif
}

__device__ __forceinline__ float fast_exp2(float x) {
#if __has_builtin(__builtin_amdgcn_exp2f)
  return __builtin_amdgcn_exp2f(x);
#else
  return exp2f(x);
#endif
}

// async global->LDS, 16B per lane. LDS dest must be wave-uniform base +
// lane*16B (linear); swizzled layouts come from pre-swizzling the per-lane
// GLOBAL source address (m97/m173 pattern).
__device__ __forceinline__ void async16(const void* g, void* l) {
  const u32_as1* gp = (const u32_as1*)(uintptr_t)g;
  u32_as3* lp = (u32_as3*)(uintptr_t)l;
  __builtin_amdgcn_global_load_lds(gp, lp, 16, 0, 0);
}

template <int N> __device__ __forceinline__ void wait_vmcnt() {
  if constexpr (N == 0)      asm volatile("s_waitcnt vmcnt(0)" ::: "memory");
  else if constexpr (N == 2) asm volatile("s_waitcnt vmcnt(2)" ::: "memory");
  else if constexpr (N == 3) asm volatile("s_waitcnt vmcnt(3)" ::: "memory");
  else if constexpr (N == 4) asm volatile("s_waitcnt vmcnt(4)" ::: "memory");
  else if constexpr (N == 6) asm volatile("s_waitcnt vmcnt(6)" ::: "memory");
  else if constexpr (N == 8) asm volatile("s_waitcnt vmcnt(8)" ::: "memory");
}

// ---------------------------------------------------------------------------
// Kernel 1: fused prep — x fp32->bf16, w_qkv / w_proj transpose+cast.
// ---------------------------------------------------------------------------
__global__ __launch_bounds__(256) void prep_kernel(
    const float* __restrict__ x, const float* __restrict__ w_qkv,
    const float* __restrict__ w_proj, u16x4* __restrict__ x_bf,
    unsigned short* __restrict__ wqkvT, unsigned short* __restrict__ wprojT) {
  const int bid = blockIdx.x;
  const int t = threadIdx.x;
  if (bid < 6144) {  // convert: 6144*256 float4 = 6,291,456 float4
    const int i = bid * 256 + t;
    float4 v = ((const float4*)x)[i];
    u16x4 o;
    o[0] = f2bf(v.x); o[1] = f2bf(v.y); o[2] = f2bf(v.z); o[3] = f2bf(v.w);
    x_bf[i] = o;
    return;
  }
  // transpose+cast, 32x32 tiles with flat 256 threads
  __shared__ float tile[32][33];
  const float* w; unsigned short* wt; int N, bx, by;
  if (bid < 6144 + 1728) { const int r = bid - 6144; w = w_qkv; wt = wqkvT; N = 2304; bx = r % 72; by = r / 72; }
  else                   { const int r = bid - 7872; w = w_proj; wt = wprojT; N = 768; bx = r % 24; by = r / 24; }
  const int n0 = bx * 32, k0 = by * 32;
  const int tx = t & 31, ty = t >> 5;
#pragma unroll
  for (int r = 0; r < 4; r++)
    tile[ty + r * 8][tx] = w[(k0 + ty + r * 8) * N + n0 + tx];
  __syncthreads();
#pragma unroll
  for (int r = 0; r < 4; r++)
    wt[(n0 + ty + r * 8) * 768 + k0 + tx] = f2bf(tile[tx][ty + r * 8]);
}

// ---------------------------------------------------------------------------
// Kernel 2/4: GEMM  C[M, NT*64] = A[M,768] * Bt[N,768]^T
// 128 x (NT*64) tile, BK=32, 4 waves 2x2.
// Staging: DIRECT global_load_lds (16B/lane DMA, no VGPR round-trip) into a
// 3-stage LDS rotation, distance-2 prefetch, counted vmcnt(NLD) at each
// k-step (never drained to 0 in steady state — loads fly across barriers).
// LDS dest is linear (wave base + lane*16B); the XOR chunk swizzle is applied
// on the per-lane GLOBAL source address, so ds_read_b128 stays 2-way (free).
// Reg-staging removed: frees ~32 VGPRs -> 3 blocks/CU co-resident (was 2).
// NK=24 fully unrolled: every LDS/global offset is an immediate.
// 1-D grid, XCD-partitioned (xcd = bid&7).
// EPI=0: scatter epilogue -> q[b,h,n,d], k[b,h,n,d], vt[b,h,d,n] (bf16)
// EPI=1: out fp32 += bias
// ---------------------------------------------------------------------------
template <int EPI, int NT, int NBLK, int MINW>
__global__ __launch_bounds__(256, MINW) void gemm_bt(
    const unsigned short* __restrict__ A, const unsigned short* __restrict__ Bt,
    unsigned short* __restrict__ qb, unsigned short* __restrict__ kb,
    unsigned short* __restrict__ vtb, float* __restrict__ outp,
    const float* __restrict__ bias) {
  constexpr int STAGE = 4096 + NT * 2048;  // shorts per stage: A(128x32) | B(NT*64 x 32)
  constexpr int NK = 24;                   // 768 / 32
  constexpr int NLD = 2 + NT;              // global_load_lds per thread per tile
  __shared__ unsigned short smem[3 * STAGE];  // 3-stage rotation

  const int t = threadIdx.x;
  const int lane = t & 63, w = t >> 6;
  const int quad = lane >> 4, l15 = lane & 15;

  const int bid = blockIdx.x;
  const int xcd = bid & 7, slot = bid >> 3;
  const int m0 = (xcd * 8 + slot / NBLK) * 128;
  const int n0 = (slot % NBLK) * (NT * 64);
  const int wm = (w & 1) * 64, wn = (w >> 1) * (NT * 32);

  f32x4 acc[4][NT * 2];
  const f32x4 fzero = {0.f, 0.f, 0.f, 0.f};
#pragma unroll
  for (int i = 0; i < 4; i++)
#pragma unroll
    for (int j = 0; j < NT * 2; j++) acc[i][j] = fzero;

  // staging geometry: per wave, rows w*16+(lane>>2) and +64, 16B per lane at
  // swizzle-adjusted source k-chunk g = ((lane&3) - (srow>>1)) & 3.
  // LDS slot ldso = srow*32 + (lane&3)*8 shorts = wave-uniform + lane*16B.
  const int srow = w * 16 + (lane >> 2);
  const int scol = (((lane & 3) - (srow >> 1)) & 3) * 8;
  const unsigned short* Ag = A + (m0 + srow) * 768 + scol;
  const unsigned short* Bg = Bt + (n0 + srow) * 768 + scol;
  const int ldso = w * 512 + lane * 8;  // shorts

  auto fill = [&](int k, int stg) {
    unsigned short* As = smem + stg * STAGE;
    async16(Ag + k * 32, As + ldso);
    async16(Ag + 64 * 768 + k * 32, As + ldso + 2048);
#pragma unroll
    for (int f = 0; f < NT; f++)
      async16(Bg + f * 64 * 768 + k * 32, As + 4096 + ldso + f * 2048);
  };

  fill(0, 0);
  fill(1, 1);

#pragma unroll
  for (int k = 0; k < NK; ++k) {
    // own fill(k) is among the oldest loads: wait all-but-newest-NLD, so
    // fill(k) has landed while fill(k+1) stays in flight across the barrier.
    if (k + 1 < NK) wait_vmcnt<NLD>();
    else            wait_vmcnt<0>();
    asm volatile("s_barrier" ::: "memory");
    // stage (k+2)%3 was read at iter k-1 by all waves (barrier proves it):
    // safe to refill now, before this iter's ds_reads (T3: stage-before-read).
    if (k + 2 < NK) fill(k + 2, (k + 2) % 3);

    const unsigned short* As = smem + (k % 3) * STAGE;
    const unsigned short* Bs = As + 4096;

    bf16x8 af[4], bfr[NT * 2];
#pragma unroll
    for (int i = 0; i < 4; i++) {
      const int row = wm + i * 16 + l15;
      af[i] = ld_frag(As + row * 32 + (((quad + (row >> 1)) & 3) << 3));
    }
#pragma unroll
    for (int j = 0; j < NT * 2; j++) {
      const int row = wn + j * 16 + l15;
      bfr[j] = ld_frag(Bs + row * 32 + (((quad + (row >> 1)) & 3) << 3));
    }
#pragma unroll
    for (int i = 0; i < 4; i++)
#pragma unroll
      for (int j = 0; j < NT * 2; j++)
        acc[i][j] = __builtin_amdgcn_mfma_f32_16x16x32_bf16(af[i], bfr[j], acc[i][j], 0, 0, 0);
  }

  // Epilogue. C/D layout: row = quad*4+reg, col = lane&15 (verified m89/m91)
#pragma unroll
  for (int i = 0; i < 4; i++) {
    const int gmb = m0 + wm + i * 16 + quad * 4;
#pragma unroll
    for (int j = 0; j < NT * 2; j++) {
      const int gc = n0 + wn + j * 16 + l15;
#pragma unroll
      for (int r = 0; r < 4; r++) {
        const int gm = gmb + r;
        float v = acc[i][j][r];
        if (EPI == 0) {
          const int b = gm >> 10, tok = gm & 1023;
          const int which = (gc >= 1536) ? 2 : (gc >= 768 ? 1 : 0);
          const int rem = gc - which * 768;
          const int h = rem >> 6, d = rem & 63;
          const int bh = b * 12 + h;
          const unsigned short bv = f2bf(v);
          if (which == 0)      qb[(bh << 16) + (tok << 6) + d] = bv;
          else if (which == 1) kb[(bh << 16) + (tok << 6) + d] = bv;
          else                 vtb[(bh << 16) + (d << 10) + tok] = bv;
        } else {
          outp[gm * 768 + gc] = v + bias[gc];
        }
      }
    }
  }
}

// ---------------------------------------------------------------------------
// Kernel 3: flash attention, S^T formulation (unchanged).
// ---------------------------------------------------------------------------
#define SWZC(row, c) (((row) << 6) + ((((c) + (row)) & 7) << 3))
#define C2 0.1803368801111244f  // SCALE * log2(e) = 0.125 * 1.442695...

__global__ __launch_bounds__(256, 3) void attn_kernel(
    const unsigned short* __restrict__ qb, const unsigned short* __restrict__ kb,
    const unsigned short* __restrict__ vtb, unsigned short* __restrict__ aout) {
  __shared__ unsigned short smem[3 * 8192];  // 48 KB: 3 stages of (Ks|Vts)

  const int t = threadIdx.x;
  const int lane = t & 63, w = t >> 6;
  const int quad = lane >> 4, l15 = lane & 15;
  const int bh = blockIdx.x;                   // bh fastest: q-tiles of one head
  const int b = bh / 12, h = bh - b * 12;      // land on the SAME XCD (96%8==0)
  const int q0 = blockIdx.y * 128;
  const int base = bh << 16;                   // bh * 1024 * 64

  // Q B-fragments, loop-invariant (issued before fills: oldest vm ops)
  bf16x8 qf[2][2];
#pragma unroll
  for (int qt = 0; qt < 2; qt++)
#pragma unroll
    for (int s = 0; s < 2; s++)
      qf[qt][s] = ld_frag(qb + base + ((q0 + w * 32 + qt * 16 + l15) << 6) +
                          s * 32 + quad * 8);

  f32x4 oacc[4][2];
  const f32x4 fzero = {0.f, 0.f, 0.f, 0.f};
#pragma unroll
  for (int dt = 0; dt < 4; dt++) { oacc[dt][0] = fzero; oacc[dt][1] = fzero; }
  float lsum0 = 0.f, lsum1 = 0.f;

  // staging slots: thread t fills LDS slot (row=t>>3, chunk=t&7); source chunk
  // de-swizzled so data lands at SWZC positions.
  const int srow = t >> 3, schk = t & 7;
  const int c0 = ((schk - srow) & 7) * 8;
  const int c1 = ((schk - (srow + 32)) & 7) * 8;

  auto fillkv = [&](int tile, int buf) {
    const int kv0 = tile * 64;
    unsigned short* Ks = smem + buf * 8192;
    unsigned short* Vts = Ks + 4096;
    async16(kb + base + ((kv0 + srow) << 6) + c0, Ks + t * 8);
    async16(kb + base + ((kv0 + srow + 32) << 6) + c1, Ks + 2048 + t * 8);
    async16(vtb + base + (srow << 10) + kv0 + c0, Vts + t * 8);
    async16(vtb + base + ((srow + 32) << 10) + kv0 + c1, Vts + 2048 + t * 8);
  };

  fillkv(0, 0);
  fillkv(1, 1);
  int cur = 0;
  for (int it = 0; it < 16; ++it) {
    if (it < 15) wait_vmcnt<4>(); else wait_vmcnt<0>();
    asm volatile("s_barrier" ::: "memory");
    if (it + 2 < 16) {
      int tgt = cur + 2; if (tgt >= 3) tgt -= 3;
      fillkv(it + 2, tgt);
    }
    const unsigned short* Ks = smem + cur * 8192;
    const unsigned short* Vts = Ks + 4096;

    // S^T = K Q^T : st[tc][qt], rows kv=tc*16+quad*4+r, col q=qt*16+l15
    f32x4 st[4][2];
#pragma unroll
    for (int tc = 0; tc < 4; tc++) { st[tc][0] = fzero; st[tc][1] = fzero; }
#pragma unroll
    for (int s = 0; s < 2; s++) {
#pragma unroll
      for (int tc = 0; tc < 4; tc++) {
        const bf16x8 kf = ld_frag(Ks + SWZC(tc * 16 + l15, s * 4 + quad));
        st[tc][0] = __builtin_amdgcn_mfma_f32_16x16x32_bf16(kf, qf[0][s], st[tc][0], 0, 0, 0);
        st[tc][1] = __builtin_amdgcn_mfma_f32_16x16x32_bf16(kf, qf[1][s], st[tc][1], 0, 0, 0);
      }
    }

    // P^T = exp2(S^T*C2); per-lane partial row sums; pack to x16 B-frags.
    s16x4 pf[4][2];
#pragma unroll
    for (int tc = 0; tc < 4; tc++) {
#pragma unroll
      for (int qt = 0; qt < 2; qt++) {
        const float p0 = fast_exp2(st[tc][qt][0] * C2);
        const float p1 = fast_exp2(st[tc][qt][1] * C2);
        const float p2 = fast_exp2(st[tc][qt][2] * C2);
        const float p3 = fast_exp2(st[tc][qt][3] * C2);
        const float ps = (p0 + p1) + (p2 + p3);
        if (qt == 0) lsum0 += ps; else lsum1 += ps;
        s16x4 pk;
        pk[0] = (short)f2bf(p0); pk[1] = (short)f2bf(p1);
        pk[2] = (short)f2bf(p2); pk[3] = (short)f2bf(p3);
        pf[tc][qt] = pk;
      }
    }

    // O^T += V^T P^T : x16 MFMA, A = V^T frag (8B LDS read), B = pf (regs)
#pragma unroll
    for (int tc = 0; tc < 4; tc++) {
#pragma unroll
      for (int dt = 0; dt < 4; dt++) {
        const int row = dt * 16 + l15;
        const int addr = (row << 6) + ((((tc * 2 + (quad >> 1)) + row) & 7) << 3) +
                         ((quad & 1) << 2);
        const s16x4 vf = *(const s16x4*)(Vts + addr);
        oacc[dt][0] = mfma16(vf, pf[tc][0], oacc[dt][0]);
        oacc[dt][1] = mfma16(vf, pf[tc][1], oacc[dt][1]);
      }
    }

    cur += 1; if (cur == 3) cur = 0;
  }

  // final row-sum reduction (only cross-lane ops in the kernel)
  lsum0 += __shfl_xor(lsum0, 16); lsum0 += __shfl_xor(lsum0, 32);
  lsum1 += __shfl_xor(lsum1, 16); lsum1 += __shfl_xor(lsum1, 32);
  const float inv0 = 1.f / lsum0, inv1 = 1.f / lsum1;

  // transpose O^T -> [q][d] via LDS (pad row to 72 elems: 2-way banks only)
  __syncthreads();  // all waves done with stage buffers before reuse
  unsigned short* Ot = smem;  // 128 x 72 = 9216 shorts
#pragma unroll
  for (int dt = 0; dt < 4; dt++) {
#pragma unroll
    for (int qt = 0; qt < 2; qt++) {
      const float inv = qt == 0 ? inv0 : inv1;
      const int qrow = (w * 32 + qt * 16 + l15) * 72 + dt * 16 + quad * 4;
#pragma unroll
      for (int r = 0; r < 4; r++)
        Ot[qrow + r] = f2bf(oacc[dt][qt][r] * inv);
    }
  }
  __syncthreads();
#pragma unroll
  for (int it = 0; it < 4; it++) {
    const int q = it * 32 + (t >> 3);
    const int d0 = (t & 7) * 8;
    const u16x8 v = *(const u16x8*)(Ot + q * 72 + d0);
    *(u16x8*)(aout + (b * 1024 + q0 + q) * 768 + h * 64 + d0) = v;
  }
}

// ---------------------------------------------------------------------------
// Launch
// ---------------------------------------------------------------------------
extern "C" void kernel_launch(void* const* d_in, const int* in_sizes, int n_in,
                              void* d_out, int out_size, void* d_ws, size_t ws_size,
                              hipStream_t stream) {
  (void)in_sizes; (void)n_in; (void)out_size; (void)ws_size;
  const float* x = (const float*)d_in[0];       // [8,1024,768]
  const float* w_qkv = (const float*)d_in[1];   // [768,2304]
  const float* w_proj = (const float*)d_in[2];  // [768,768]
  const float* b_proj = (const float*)d_in[3];  // [768]
  float* out = (float*)d_out;

  char* ws = (char*)d_ws;
  unsigned short* x_bf   = (unsigned short*)(ws);              // 12,582,912 B
  unsigned short* wqkvT  = (unsigned short*)(ws + 12582912);   //  3,538,944 B
  unsigned short* wprojT = (unsigned short*)(ws + 16121856);   //  1,179,648 B
  unsigned short* qb     = (unsigned short*)(ws + 17301504);   // 12,582,912 B
  unsigned short* kb     = (unsigned short*)(ws + 29884416);   // 12,582,912 B
  unsigned short* vtb    = (unsigned short*)(ws + 42467328);   // 12,582,912 B
  unsigned short* aout   = x_bf;  // reuse: x_bf dead after GEMM1

  prep_kernel<<<8448, 256, 0, stream>>>(x, w_qkv, w_proj, (u16x4*)x_bf, wqkvT, wprojT);
  gemm_bt<0, 2, 18, 3><<<1152, 256, 0, stream>>>(x_bf, wqkvT, qb, kb, vtb, nullptr, nullptr);
  attn_kernel<<<dim3(96, 8), 256, 0, stream>>>(qb, kb, vtb, aout);
  gemm_bt<1, 1, 12, 4><<<768, 256, 0, stream>>>(aout, wprojT, nullptr, nullptr, nullptr, out, b_proj);
}

// Round 2
// 184.831 us; speedup vs baseline: 1.0523x; 1.0523x over previous
//
#include <hip/hip_runtime.h>
#include <stdint.h>

// ---------------------------------------------------------------------------
// Types
// ---------------------------------------------------------------------------
typedef __attribute__((ext_vector_type(8))) __bf16 bf16x8;
typedef __attribute__((ext_vector_type(8))) unsigned short u16x8;
typedef __attribute__((ext_vector_type(4))) unsigned short u16x4;
typedef __attribute__((ext_vector_type(4))) short s16x4;
typedef __attribute__((ext_vector_type(4))) float f32x4;

typedef unsigned int u32_as1 __attribute__((address_space(1)));
typedef unsigned int u32_as3 __attribute__((address_space(3)));

// fp32 -> bf16 round-to-nearest-even (inputs are finite normals; no NaN path)
__device__ __forceinline__ unsigned short f2bf(float f) {
  unsigned int u = __float_as_uint(f);
  u += 0x7fffu + ((u >> 16) & 1u);
  return (unsigned short)(u >> 16);
}

__device__ __forceinline__ bf16x8 ld_frag(const unsigned short* p) {
  return __builtin_bit_cast(bf16x8, *(const u16x8*)p);
}

// K=16 bf16 MFMA: A/B are 4 bf16 (as short4). C row=quad*4+r, col=lane&15;
// A[m=lane&15][k=quad*4+j]; B[k=quad*4+j][n=lane&15].
__device__ __forceinline__ f32x4 mfma16(s16x4 a, s16x4 b, f32x4 c) {
#if __has_builtin(__builtin_amdgcn_mfma_f32_16x16x16bf16_1k)
  return __builtin_amdgcn_mfma_f32_16x16x16bf16_1k(a, b, c, 0, 0, 0);
#elif __has_builtin(__builtin_amdgcn_mfma_f32_16x16x16_bf16_1k)
  return __builtin_amdgcn_mfma_f32_16x16x16_bf16_1k(a, b, c, 0, 0, 0);
#else
  asm volatile("v_mfma_f32_16x16x16_bf16 %0, %1, %2, %0"
               : "+v"(c) : "v"(a), "v"(b));
  return c;
#endif
}

__device__ __forceinline__ float fast_exp2(float x) {
#if __has_builtin(__builtin_amdgcn_exp2f)
  return __builtin_amdgcn_exp2f(x);
#else
  return exp2f(x);
#endif
}

// async global->LDS, 16B per lane. LDS dest must be wave-uniform base +
// lane*16B (linear); swizzled layouts come from pre-swizzling the per-lane
// GLOBAL source address (m97/m173 pattern).
__device__ __forceinline__ void async16(const void* g, void* l) {
  const u32_as1* gp = (const u32_as1*)(uintptr_t)g;
  u32_as3* lp = (u32_as3*)(uintptr_t)l;
  __builtin_amdgcn_global_load_lds(gp, lp, 16, 0, 0);
}

template <int N> __device__ __forceinline__ void wait_vmcnt() {
  if constexpr (N == 0)      asm volatile("s_waitcnt vmcnt(0)" ::: "memory");
  else if constexpr (N == 4) asm volatile("s_waitcnt vmcnt(4)" ::: "memory");
  else if constexpr (N == 6) asm volatile("s_waitcnt vmcnt(6)" ::: "memory");
}

// ---------------------------------------------------------------------------
// Kernel 1: fused prep — x fp32->bf16, w_qkv / w_proj transpose+cast.
// ---------------------------------------------------------------------------
__global__ __launch_bounds__(256) void prep_kernel(
    const float* __restrict__ x, const float* __restrict__ w_qkv,
    const float* __restrict__ w_proj, u16x4* __restrict__ x_bf,
    unsigned short* __restrict__ wqkvT, unsigned short* __restrict__ wprojT) {
  const int bid = blockIdx.x;
  const int t = threadIdx.x;
  if (bid < 6144) {  // convert: 6144*256 float4 = 6,291,456 float4
    const int i = bid * 256 + t;
    float4 v = ((const float4*)x)[i];
    u16x4 o;
    o[0] = f2bf(v.x); o[1] = f2bf(v.y); o[2] = f2bf(v.z); o[3] = f2bf(v.w);
    x_bf[i] = o;
    return;
  }
  // transpose+cast, 32x32 tiles with flat 256 threads
  __shared__ float tile[32][33];
  const float* w; unsigned short* wt; int N, bx, by;
  if (bid < 6144 + 1728) { const int r = bid - 6144; w = w_qkv; wt = wqkvT; N = 2304; bx = r % 72; by = r / 72; }
  else                   { const int r = bid - 7872; w = w_proj; wt = wprojT; N = 768; bx = r % 24; by = r / 24; }
  const int n0 = bx * 32, k0 = by * 32;
  const int tx = t & 31, ty = t >> 5;
#pragma unroll
  for (int r = 0; r < 4; r++)
    tile[ty + r * 8][tx] = w[(k0 + ty + r * 8) * N + n0 + tx];
  __syncthreads();
#pragma unroll
  for (int r = 0; r < 4; r++)
    wt[(n0 + ty + r * 8) * 768 + k0 + tx] = f2bf(tile[tx][ty + r * 8]);
}

// ---------------------------------------------------------------------------
// Kernel 2/4: GEMM  C[M, 128-col tile] = A[M,768] * Bt[N,768]^T
// 256x128 tile, BK=64, 8 waves (512 thr) as 4m x 2n; per-wave C = 64x64
// (acc[4][4] f32x4 = 64 AGPR).
// Deep pipeline (T3+T4+T5): 3 TRUE LDS stages (48 KB each, 144 KB total,
// 1 block/CU), 2 phases per K-tile (one kk=32 slice each):
//   { vmcnt(6) [ph0 only]; s_barrier; 8x ds_read_b128; issue 3x
//     global_load_lds of stage t+2; setprio(1); 16x MFMA; setprio(0) }
// vmcnt(6) derivation: at tile-t top the only newer loads are stage(t+1)'s
// 6, so vmcnt(6) == "stage(t) fully landed". Never drains to 0 until the
// last tile. Stage t+2 writes buf (t+2)%3, last read at tile t-1 — fully
// barrier-separated, no half-tile hazards.
// T2: LDS chunk-XOR swizzle ch^=(row&7) — every wave b128 read sits at the
// uniform 8-req/bank floor; applied via pre-swizzled GLOBAL source (linear
// LDS dest, rule 21) and the same XOR on the read side.
// Grid: 1-D, XCD-partitioned (xcd=bid&7), m-minor within XCD so concurrent
// per-XCD working set (~3.2 MB) fits the 4 MB L2.
// EPI=0: scatter epilogue -> q[b,h,n,d], k[b,h,n,d], vt[b,h,d,n] (bf16)
// EPI=1: out fp32 += bias
// ---------------------------------------------------------------------------
template <int EPI>
__global__ __launch_bounds__(512, 2) void gemm256(
    const unsigned short* __restrict__ A, const unsigned short* __restrict__ Bt,
    unsigned short* __restrict__ qb, unsigned short* __restrict__ kb,
    unsigned short* __restrict__ vtb, float* __restrict__ outp,
    const float* __restrict__ bias) {
  constexpr int NKT = 12;    // 768 / 64
  constexpr int SSH = 24576; // shorts per stage: A 256x64 (16384) | B 128x64 (8192)
  __shared__ unsigned short smem[3 * SSH];  // 147456 B

  const int t = threadIdx.x;                 // 0..511
  const int lane = t & 63, w = t >> 6;       // 8 waves
  const int quad = lane >> 4, l15 = lane & 15;
  const int wm = w >> 1, wn = w & 1;         // 4 m-bands x 2 n-bands

  const int bid = blockIdx.x;
  const int xcd = bid & 7, slot = bid >> 3;
  const int m0 = (xcd * 4 + (slot & 3)) * 256;  // m-minor: 4 m-panels/XCD
  const int n0 = (slot >> 2) * 128;

  // per-lane frag LDS offsets (shorts), loop-invariant.
  // logical chunk for (kk,quad) = kk*4+quad; phys = logical ^ (row&7).
  int aoff[4][2], boff[4][2];
#pragma unroll
  for (int i = 0; i < 4; i++) {
    const int row = wm * 64 + i * 16 + l15;
    const int rs = row & 7;
#pragma unroll
    for (int kk = 0; kk < 2; kk++)
      aoff[i][kk] = row * 64 + (((kk * 4 + quad) ^ rs) << 3);
  }
#pragma unroll
  for (int j = 0; j < 4; j++) {
    const int row = wn * 64 + j * 16 + l15;
    const int rs = row & 7;
#pragma unroll
    for (int kk = 0; kk < 2; kk++)
      boff[j][kk] = 16384 + row * 64 + (((kk * 4 + quad) ^ rs) << 3);
  }

  // staging: thread t owns LDS slot t*16B (linear -> DMA-compatible);
  // that slot is (row = base + t/8, phys chunk = t&7); source supplies
  // logical chunk g = (t&7) ^ (row&7)  [row&7 == (t>>3)&7 since bases %8==0].
  const int srow = t >> 3;                       // 0..63
  const int gch = ((t & 7) ^ (srow & 7)) << 3;   // source col offset (shorts)
  const unsigned short* Ags = A + (m0 + srow) * 768 + gch;
  const unsigned short* Bgs = Bt + (n0 + srow) * 768 + gch;

  f32x4 acc[4][4];
  const f32x4 fzero = {0.f, 0.f, 0.f, 0.f};
#pragma unroll
  for (int i = 0; i < 4; i++)
#pragma unroll
    for (int j = 0; j < 4; j++) acc[i][j] = fzero;

  // 6 loads per K-tile per thread, split 3+3 across the 2 phases.
  auto stage = [&](int kt, int part) {
    unsigned short* s = smem + (kt % 3) * SSH + t * 8;
    const int ko = kt * 64;
    if (part == 0) {  // A rows 0..191 (3 x 64-row groups)
      async16(Ags + ko, s);
      async16(Ags + 49152 + ko, s + 4096);    // 49152 = 64*768
      async16(Ags + 98304 + ko, s + 8192);
    } else {          // A rows 192..255 + B rows 0..127
      async16(Ags + 147456 + ko, s + 12288);
      async16(Bgs + ko, s + 16384);
      async16(Bgs + 49152 + ko, s + 20480);
    }
  };

  stage(0, 0); stage(0, 1);
  stage(1, 0); stage(1, 1);

#pragma unroll
  for (int kt = 0; kt < NKT; ++kt) {
    const unsigned short* S = smem + (kt % 3) * SSH;
#pragma unroll
    for (int ph = 0; ph < 2; ++ph) {
      if (ph == 0) {
        if (kt < NKT - 1) wait_vmcnt<6>();  // == stage(kt) landed
        else              wait_vmcnt<0>();
      }
      __builtin_amdgcn_s_barrier();  // all waves' stage(kt) landed / lockstep

      bf16x8 af[4], bf[4];
#pragma unroll
      for (int i = 0; i < 4; i++) af[i] = ld_frag(S + aoff[i][ph]);
#pragma unroll
      for (int j = 0; j < 4; j++) bf[j] = ld_frag(S + boff[j][ph]);

      if (kt + 2 < NKT) stage(kt + 2, ph);  // DMA flies across barriers

      __builtin_amdgcn_s_setprio(1);
#pragma unroll
      for (int i = 0; i < 4; i++)
#pragma unroll
        for (int j = 0; j < 4; j++)
          acc[i][j] = __builtin_amdgcn_mfma_f32_16x16x32_bf16(af[i], bf[j], acc[i][j], 0, 0, 0);
      __builtin_amdgcn_s_setprio(0);
    }
  }

  // Epilogue. C/D layout: row = quad*4+reg, col = lane&15 (verified m89/m91)
#pragma unroll
  for (int i = 0; i < 4; i++) {
    const int gmb = m0 + wm * 64 + i * 16 + quad * 4;
#pragma unroll
    for (int j = 0; j < 4; j++) {
      const int gc = n0 + wn * 64 + j * 16 + l15;
#pragma unroll
      for (int r = 0; r < 4; r++) {
        const int gm = gmb + r;
        float v = acc[i][j][r];
        if (EPI == 0) {
          const int b = gm >> 10, tok = gm & 1023;
          const int which = (gc >= 1536) ? 2 : (gc >= 768 ? 1 : 0);
          const int rem = gc - which * 768;
          const int h = rem >> 6, d = rem & 63;
          const int bh = b * 12 + h;
          const unsigned short bv = f2bf(v);
          if (which == 0)      qb[(bh << 16) + (tok << 6) + d] = bv;
          else if (which == 1) kb[(bh << 16) + (tok << 6) + d] = bv;
          else                 vtb[(bh << 16) + (d << 10) + tok] = bv;
        } else {
          outp[gm * 768 + gc] = v + bias[gc];
        }
      }
    }
  }
}

// ---------------------------------------------------------------------------
// Kernel 3: flash attention, S^T formulation (unchanged).
// ---------------------------------------------------------------------------
#define SWZC(row, c) (((row) << 6) + ((((c) + (row)) & 7) << 3))
#define C2 0.1803368801111244f  // SCALE * log2(e) = 0.125 * 1.442695...

__global__ __launch_bounds__(256, 3) void attn_kernel(
    const unsigned short* __restrict__ qb, const unsigned short* __restrict__ kb,
    const unsigned short* __restrict__ vtb, unsigned short* __restrict__ aout) {
  __shared__ unsigned short smem[3 * 8192];  // 48 KB: 3 stages of (Ks|Vts)

  const int t = threadIdx.x;
  const int lane = t & 63, w = t >> 6;
  const int quad = lane >> 4, l15 = lane & 15;
  const int bh = blockIdx.x;                   // bh fastest: q-tiles of one head
  const int b = bh / 12, h = bh - b * 12;      // land on the SAME XCD (96%8==0)
  const int q0 = blockIdx.y * 128;
  const int base = bh << 16;                   // bh * 1024 * 64

  // Q B-fragments, loop-invariant (issued before fills: oldest vm ops)
  bf16x8 qf[2][2];
#pragma unroll
  for (int qt = 0; qt < 2; qt++)
#pragma unroll
    for (int s = 0; s < 2; s++)
      qf[qt][s] = ld_frag(qb + base + ((q0 + w * 32 + qt * 16 + l15) << 6) +
                          s * 32 + quad * 8);

  f32x4 oacc[4][2];
  const f32x4 fzero = {0.f, 0.f, 0.f, 0.f};
#pragma unroll
  for (int dt = 0; dt < 4; dt++) { oacc[dt][0] = fzero; oacc[dt][1] = fzero; }
  float lsum0 = 0.f, lsum1 = 0.f;

  // staging slots: thread t fills LDS slot (row=t>>3, chunk=t&7); source chunk
  // de-swizzled so data lands at SWZC positions.
  const int srow = t >> 3, schk = t & 7;
  const int c0 = ((schk - srow) & 7) * 8;
  const int c1 = ((schk - (srow + 32)) & 7) * 8;

  auto fillkv = [&](int tile, int buf) {
    const int kv0 = tile * 64;
    unsigned short* Ks = smem + buf * 8192;
    unsigned short* Vts = Ks + 4096;
    async16(kb + base + ((kv0 + srow) << 6) + c0, Ks + t * 8);
    async16(kb + base + ((kv0 + srow + 32) << 6) + c1, Ks + 2048 + t * 8);
    async16(vtb + base + (srow << 10) + kv0 + c0, Vts + t * 8);
    async16(vtb + base + ((srow + 32) << 10) + kv0 + c1, Vts + 2048 + t * 8);
  };

  fillkv(0, 0);
  fillkv(1, 1);
  int cur = 0;
  for (int it = 0; it < 16; ++it) {
    if (it < 15) wait_vmcnt<4>(); else wait_vmcnt<0>();
    asm volatile("s_barrier" ::: "memory");
    if (it + 2 < 16) {
      int tgt = cur + 2; if (tgt >= 3) tgt -= 3;
      fillkv(it + 2, tgt);
    }
    const unsigned short* Ks = smem + cur * 8192;
    const unsigned short* Vts = Ks + 4096;

    // S^T = K Q^T : st[tc][qt], rows kv=tc*16+quad*4+r, col q=qt*16+l15
    f32x4 st[4][2];
#pragma unroll
    for (int tc = 0; tc < 4; tc++) { st[tc][0] = fzero; st[tc][1] = fzero; }
#pragma unroll
    for (int s = 0; s < 2; s++) {
#pragma unroll
      for (int tc = 0; tc < 4; tc++) {
        const bf16x8 kf = ld_frag(Ks + SWZC(tc * 16 + l15, s * 4 + quad));
        st[tc][0] = __builtin_amdgcn_mfma_f32_16x16x32_bf16(kf, qf[0][s], st[tc][0], 0, 0, 0);
        st[tc][1] = __builtin_amdgcn_mfma_f32_16x16x32_bf16(kf, qf[1][s], st[tc][1], 0, 0, 0);
      }
    }

    // P^T = exp2(S^T*C2); per-lane partial row sums; pack to x16 B-frags.
    s16x4 pf[4][2];
#pragma unroll
    for (int tc = 0; tc < 4; tc++) {
#pragma unroll
      for (int qt = 0; qt < 2; qt++) {
        const float p0 = fast_exp2(st[tc][qt][0] * C2);
        const float p1 = fast_exp2(st[tc][qt][1] * C2);
        const float p2 = fast_exp2(st[tc][qt][2] * C2);
        const float p3 = fast_exp2(st[tc][qt][3] * C2);
        const float ps = (p0 + p1) + (p2 + p3);
        if (qt == 0) lsum0 += ps; else lsum1 += ps;
        s16x4 pk;
        pk[0] = (short)f2bf(p0); pk[1] = (short)f2bf(p1);
        pk[2] = (short)f2bf(p2); pk[3] = (short)f2bf(p3);
        pf[tc][qt] = pk;
      }
    }

    // O^T += V^T P^T : x16 MFMA, A = V^T frag (8B LDS read), B = pf (regs)
#pragma unroll
    for (int tc = 0; tc < 4; tc++) {
#pragma unroll
      for (int dt = 0; dt < 4; dt++) {
        const int row = dt * 16 + l15;
        const int addr = (row << 6) + ((((tc * 2 + (quad >> 1)) + row) & 7) << 3) +
                         ((quad & 1) << 2);
        const s16x4 vf = *(const s16x4*)(Vts + addr);
        oacc[dt][0] = mfma16(vf, pf[tc][0], oacc[dt][0]);
        oacc[dt][1] = mfma16(vf, pf[tc][1], oacc[dt][1]);
      }
    }

    cur += 1; if (cur == 3) cur = 0;
  }

  // final row-sum reduction (only cross-lane ops in the kernel)
  lsum0 += __shfl_xor(lsum0, 16); lsum0 += __shfl_xor(lsum0, 32);
  lsum1 += __shfl_xor(lsum1, 16); lsum1 += __shfl_xor(lsum1, 32);
  const float inv0 = 1.f / lsum0, inv1 = 1.f / lsum1;

  // transpose O^T -> [q][d] via LDS (pad row to 72 elems: 2-way banks only)
  __syncthreads();  // all waves done with stage buffers before reuse
  unsigned short* Ot = smem;  // 128 x 72 = 9216 shorts
#pragma unroll
  for (int dt = 0; dt < 4; dt++) {
#pragma unroll
    for (int qt = 0; qt < 2; qt++) {
      const float inv = qt == 0 ? inv0 : inv1;
      const int qrow = (w * 32 + qt * 16 + l15) * 72 + dt * 16 + quad * 4;
#pragma unroll
      for (int r = 0; r < 4; r++)
        Ot[qrow + r] = f2bf(oacc[dt][qt][r] * inv);
    }
  }
  __syncthreads();
#pragma unroll
  for (int it = 0; it < 4; it++) {
    const int q = it * 32 + (t >> 3);
    const int d0 = (t & 7) * 8;
    const u16x8 v = *(const u16x8*)(Ot + q * 72 + d0);
    *(u16x8*)(aout + (b * 1024 + q0 + q) * 768 + h * 64 + d0) = v;
  }
}

// ---------------------------------------------------------------------------
// Launch
// ---------------------------------------------------------------------------
extern "C" void kernel_launch(void* const* d_in, const int* in_sizes, int n_in,
                              void* d_out, int out_size, void* d_ws, size_t ws_size,
                              hipStream_t stream) {
  (void)in_sizes; (void)n_in; (void)out_size; (void)ws_size;
  const float* x = (const float*)d_in[0];       // [8,1024,768]
  const float* w_qkv = (const float*)d_in[1];   // [768,2304]
  const float* w_proj = (const float*)d_in[2];  // [768,768]
  const float* b_proj = (const float*)d_in[3];  // [768]
  float* out = (float*)d_out;

  char* ws = (char*)d_ws;
  unsigned short* x_bf   = (unsigned short*)(ws);              // 12,582,912 B
  unsigned short* wqkvT  = (unsigned short*)(ws + 12582912);   //  3,538,944 B
  unsigned short* wprojT = (unsigned short*)(ws + 16121856);   //  1,179,648 B
  unsigned short* qb     = (unsigned short*)(ws + 17301504);   // 12,582,912 B
  unsigned short* kb     = (unsigned short*)(ws + 29884416);   // 12,582,912 B
  unsigned short* vtb    = (unsigned short*)(ws + 42467328);   // 12,582,912 B
  unsigned short* aout   = x_bf;  // reuse: x_bf dead after GEMM1

  prep_kernel<<<8448, 256, 0, stream>>>(x, w_qkv, w_proj, (u16x4*)x_bf, wqkvT, wprojT);
  gemm256<0><<<576, 512, 0, stream>>>(x_bf, wqkvT, qb, kb, vtb, nullptr, nullptr);
  attn_kernel<<<dim3(96, 8), 256, 0, stream>>>(qb, kb, vtb, aout);
  gemm256<1><<<192, 512, 0, stream>>>(aout, wprojT, nullptr, nullptr, nullptr, out, b_proj);
}